// Round 6
// baseline (54976.929 us; speedup 1.0000x reference)
//
#include <hip/hip_runtime.h>
#include <hip/hip_fp16.h>

#define Hh 2048
#define VV 256
#define SS 2048
#define TT 2048
#define NB 256
#define NT 512

typedef _Float16 h4 __attribute__((ext_vector_type(4)));
typedef _Float16 h2 __attribute__((ext_vector_type(2)));
typedef unsigned int u32x4 __attribute__((ext_vector_type(4)));

#if defined(__has_builtin)
#if __has_builtin(__builtin_amdgcn_fdot2)
#define FDOT2(a, b, c) __builtin_amdgcn_fdot2((a), (b), (c), false)
#endif
#endif
#ifndef FDOT2
#define FDOT2(a, b, c) \
  fmaf((float)(a).x, (float)(b).x, fmaf((float)(a).y, (float)(b).y, (c)))
#endif

#define SH(v, a, b) __builtin_shufflevector((v), (v), (a), (b))

static __device__ __forceinline__ h2 mk2(unsigned int a, unsigned int b) {
  h2 r;
  r.x = __builtin_bit_cast(_Float16, (unsigned short)a);
  r.y = __builtin_bit_cast(_Float16, (unsigned short)b);
  return r;
}

// ---------------------------------------------------------------------------
// Generic NT GEMM: C[M][N] = A[M,K] . B[N,K]^T (+ biasM[m]) (+ biasN[n])
// ---------------------------------------------------------------------------
__global__ __launch_bounds__(256) void gemm_nt(const float* __restrict__ A,
                                               const float* __restrict__ B,
                                               const float* __restrict__ biasM,
                                               const float* __restrict__ biasN,
                                               float* __restrict__ C,
                                               int M, int N, int K) {
  __shared__ __align__(16) float At[32][68];
  __shared__ __align__(16) float Bt[32][68];
  const int t = threadIdx.x;
  const int m0 = blockIdx.x << 6, n0 = blockIdx.y << 6;
  const int r0 = t >> 3, c4 = (t & 7) << 2;
  const int tm = (t >> 4) << 2, tn = (t & 15) << 2;
  float acc[4][4];
#pragma unroll
  for (int i = 0; i < 4; ++i)
#pragma unroll
    for (int j = 0; j < 4; ++j) acc[i][j] = 0.f;

  for (int k0 = 0; k0 < K; k0 += 32) {
    float4 a0 = *(const float4*)&A[(size_t)(m0 + r0) * K + k0 + c4];
    float4 a1 = *(const float4*)&A[(size_t)(m0 + r0 + 32) * K + k0 + c4];
    float4 b0 = *(const float4*)&B[(size_t)(n0 + r0) * K + k0 + c4];
    float4 b1 = *(const float4*)&B[(size_t)(n0 + r0 + 32) * K + k0 + c4];
    __syncthreads();
    At[c4 + 0][r0] = a0.x; At[c4 + 1][r0] = a0.y; At[c4 + 2][r0] = a0.z; At[c4 + 3][r0] = a0.w;
    At[c4 + 0][r0 + 32] = a1.x; At[c4 + 1][r0 + 32] = a1.y; At[c4 + 2][r0 + 32] = a1.z; At[c4 + 3][r0 + 32] = a1.w;
    Bt[c4 + 0][r0] = b0.x; Bt[c4 + 1][r0] = b0.y; Bt[c4 + 2][r0] = b0.z; Bt[c4 + 3][r0] = b0.w;
    Bt[c4 + 0][r0 + 32] = b1.x; Bt[c4 + 1][r0 + 32] = b1.y; Bt[c4 + 2][r0 + 32] = b1.z; Bt[c4 + 3][r0 + 32] = b1.w;
    __syncthreads();
#pragma unroll
    for (int k = 0; k < 32; ++k) {
      float4 av = *(const float4*)&At[k][tm];
      float4 bv = *(const float4*)&Bt[k][tn];
      acc[0][0] = fmaf(av.x, bv.x, acc[0][0]);
      acc[0][1] = fmaf(av.x, bv.y, acc[0][1]);
      acc[0][2] = fmaf(av.x, bv.z, acc[0][2]);
      acc[0][3] = fmaf(av.x, bv.w, acc[0][3]);
      acc[1][0] = fmaf(av.y, bv.x, acc[1][0]);
      acc[1][1] = fmaf(av.y, bv.y, acc[1][1]);
      acc[1][2] = fmaf(av.y, bv.z, acc[1][2]);
      acc[1][3] = fmaf(av.y, bv.w, acc[1][3]);
      acc[2][0] = fmaf(av.z, bv.x, acc[2][0]);
      acc[2][1] = fmaf(av.z, bv.y, acc[2][1]);
      acc[2][2] = fmaf(av.z, bv.z, acc[2][2]);
      acc[2][3] = fmaf(av.z, bv.w, acc[2][3]);
      acc[3][0] = fmaf(av.w, bv.x, acc[3][0]);
      acc[3][1] = fmaf(av.w, bv.y, acc[3][1]);
      acc[3][2] = fmaf(av.w, bv.z, acc[3][2]);
      acc[3][3] = fmaf(av.w, bv.w, acc[3][3]);
    }
  }
#pragma unroll
  for (int i = 0; i < 4; ++i) {
    float bm = biasM ? biasM[m0 + tm + i] : 0.f;
#pragma unroll
    for (int j = 0; j < 4; ++j) {
      float bn = biasN ? biasN[n0 + tn + j] : 0.f;
      C[(size_t)(m0 + tm + i) * N + n0 + tn + j] = acc[i][j] + bm + bn;
    }
  }
}

// ---------------------------------------------------------------------------
// Persistent recurrence kernel — WAVE-autonomous tagged dataflow.
//
// hb: compact uint32[2][2048]; slot = (16-bit epoch tag << 16 | fp16 h bits).
// Epoch e (h after step e-1... tag e+1) lives in buffer e&1. Producer at step
// s publishes tag s+2 into buffer (s+1)&1 via relaxed agent store (the R1
// publish — R5's atomic-swap regressed). Init: owner block writes tag 1.
//
// NEW STRUCTURE: zero intra-block coupling. No LDS h buffer, no per-step
// __syncthreads. Lane l of EVERY wave polls its own 128 B line = slots
// 32l..32l+31 (= h[32l..32l+31]); weights for the wave's row, columns
// 32l..32l+31, live in 48 VGPRs/lane (24 x h4). Detection = the read: h goes
// straight to registers, lane-local partial dot, 64-lane shuffle reduce.
// Two-phase poll keeps per-line request rate AT the R1 level: spin (with
// s_sleep) on a 16 B sentinel quarter-line, then one-shot load+verify the
// remaining 112 B (near-certain pass: slots fill within one service sweep).
// Verified slots are immutable until overwritten 2 epochs later, so sentinel
// values are safely reused.
//
// Safety (wave-granular transitive chain): wave W at step s overwrites a
// buffer-(s+1)&1 slot holding tag s (epoch s-1). W publishes tag s+2 only
// after detecting ALL tags s+1 — and each wave V published its tag s+1 only
// after V READ (into registers) every slot of epoch s-1... wait, V published
// s+1 at the end of V's step s-1, which required V to have detected+read ALL
// of epoch s-1. Hence every reader of the overwritten epoch finished its
// read before W's overwrite. Exact-match tag compares make stale values
// (older tags, incl. previous graph replay's) harmless; max tag 4097 < 2^16.
// ---------------------------------------------------------------------------
__global__ __launch_bounds__(NT, 2) void recur_kernel(
    const float* __restrict__ giT_enc, const float* __restrict__ giT_dec,
    const float* __restrict__ enc_w_hh, const float* __restrict__ enc_b_hh,
    const float* __restrict__ dec_w_hh, const float* __restrict__ dec_b_hh,
    const int* __restrict__ inputs, const int* __restrict__ targets,
    unsigned int* __restrict__ hb, float* __restrict__ dec_hs) {
  __shared__ __align__(16) float gi_lds[24 * VV];       // 24 KB
  __shared__ __align__(16) unsigned short tok_lds[SS];  // 4 KB
  __shared__ float gidec_lds[48];

  const int t = threadIdx.x;
  const int b = blockIdx.x;
  const int bks = b << 3;
  const int w = t >> 6, l = t & 63;

  // ---- recurrent weights + biases: lane l holds cols 32l..32l+31 of the
  //      wave's 3 gate rows (row index bks+w) as 24 x h4 (48 VGPRs)
  h4 wreg[24];
  float br_, bz_, bn_;
  auto load_wb = [&](const float* W, const float* B) {
#pragma unroll
    for (int g = 0; g < 3; ++g) {
      const float* rb = W + ((size_t)(g * Hh + bks + w)) * Hh + (l << 5);
#pragma unroll
      for (int q = 0; q < 8; ++q) {
        float4 vv = *(const float4*)&rb[q * 4];
        wreg[g * 8 + q] = h4{(_Float16)vv.x, (_Float16)vv.y,
                            (_Float16)vv.z, (_Float16)vv.w};
      }
    }
    br_ = B[bks + w];
    bz_ = B[Hh + bks + w];
    bn_ = B[2 * Hh + bks + w];
  };
  load_wb(enc_w_hh, enc_b_hh);

  // ---- stage encoder per-vocab input-gate slice: gi_lds[(g*8+j)*256 + v]
  for (int r = 0; r < 24; ++r) {
    const int g = r >> 3, j = r & 7;
    const float4* src = (const float4*)(giT_enc + ((size_t)(g * Hh + bks + j)) * VV);
    if (t < 64) ((float4*)&gi_lds[r * VV])[t] = src[t];
  }

  // ---- tokens
  for (int u = t; u < SS; u += NT) tok_lds[u] = (unsigned short)inputs[u];

  // ---- decoder input-gates: only tokens {0, targets[1]}
  if (t < 48) {
    const int sel = t / 24, r = t % 24;
    const int tk = sel ? targets[1] : 0;
    const int g = r >> 3, jj = r & 7;
    gidec_lds[sel * 24 + r] = giT_dec[((size_t)(g * Hh + bks + jj)) * VV + tk];
  }

  // ---- init own h slots: fp16 0.0 (bits 0), tag 1 (buffer 0)
  if (t < 8) {
    __hip_atomic_store(&hb[bks + t], 0x00010000u, __ATOMIC_RELAXED,
                       __HIP_MEMORY_SCOPE_AGENT);
  }
  __syncthreads();  // gi_lds / tok_lds / gidec_lds ready (one-time)
  float hprev = 0.0f;  // lane 0 of wave w: running fp32 h[bks+w]

  for (int step = 0; step < SS + TT; ++step) {
    if (step == SS) load_wb(dec_w_hh, dec_b_hh);  // private regs: no hazard
    const int sb = step & 1;
    const unsigned int want = ((unsigned int)(step + 1)) << 16;
    const unsigned int* addr = hb + ((size_t)sb << 11) + (l << 5);

    // ---- phase 1: sentinel spin on the last 16 B of this lane's line
    u32x4 s7;
    for (;;) {
      asm volatile(
          "global_load_dwordx4 %0, %1, off offset:112 sc0 sc1\n\t"
          "s_waitcnt vmcnt(0)"
          : "=&v"(s7)
          : "v"(addr)
          : "memory");
      if ((((s7.x ^ want) | (s7.y ^ want) | (s7.z ^ want) | (s7.w ^ want)) &
           0xFFFF0000u) == 0u)
        break;
      __builtin_amdgcn_s_sleep(1);
    }

    // ---- phase 2: one-shot load+verify of the remaining 112 B
    u32x4 v0, v1, v2, v3, v4, v5, v6;
    for (;;) {
      asm volatile(
          "global_load_dwordx4 %0, %7, off sc0 sc1\n\t"
          "global_load_dwordx4 %1, %7, off offset:16 sc0 sc1\n\t"
          "global_load_dwordx4 %2, %7, off offset:32 sc0 sc1\n\t"
          "global_load_dwordx4 %3, %7, off offset:48 sc0 sc1\n\t"
          "global_load_dwordx4 %4, %7, off offset:64 sc0 sc1\n\t"
          "global_load_dwordx4 %5, %7, off offset:80 sc0 sc1\n\t"
          "global_load_dwordx4 %6, %7, off offset:96 sc0 sc1\n\t"
          "s_waitcnt vmcnt(0)"
          : "=&v"(v0), "=&v"(v1), "=&v"(v2), "=&v"(v3), "=&v"(v4), "=&v"(v5),
            "=&v"(v6)
          : "v"(addr)
          : "memory");
      unsigned int bad = (v0.x ^ want) | (v0.y ^ want) | (v0.z ^ want) | (v0.w ^ want);
      bad |= (v1.x ^ want) | (v1.y ^ want) | (v1.z ^ want) | (v1.w ^ want);
      bad |= (v2.x ^ want) | (v2.y ^ want) | (v2.z ^ want) | (v2.w ^ want);
      bad |= (v3.x ^ want) | (v3.y ^ want) | (v3.z ^ want) | (v3.w ^ want);
      bad |= (v4.x ^ want) | (v4.y ^ want) | (v4.z ^ want) | (v4.w ^ want);
      bad |= (v5.x ^ want) | (v5.y ^ want) | (v5.z ^ want) | (v5.w ^ want);
      bad |= (v6.x ^ want) | (v6.y ^ want) | (v6.z ^ want) | (v6.w ^ want);
      if ((bad & 0xFFFF0000u) == 0u) break;
    }

    // ---- lane-local partial dots over h[32l..32l+31] (fp16 dot2, fp32 acc)
    float ar = 0.f, az = 0.f, an = 0.f;
#define DOQ(q, vq)                                        \
  {                                                       \
    h2 hlo = mk2((vq).x, (vq).y);                         \
    h2 hhi = mk2((vq).z, (vq).w);                         \
    h4 wr4 = wreg[q];                                     \
    h4 wz4 = wreg[8 + (q)];                               \
    h4 wn4 = wreg[16 + (q)];                              \
    ar = FDOT2(SH(wr4, 0, 1), hlo, ar);                   \
    ar = FDOT2(SH(wr4, 2, 3), hhi, ar);                   \
    az = FDOT2(SH(wz4, 0, 1), hlo, az);                   \
    az = FDOT2(SH(wz4, 2, 3), hhi, az);                   \
    an = FDOT2(SH(wn4, 0, 1), hlo, an);                   \
    an = FDOT2(SH(wn4, 2, 3), hhi, an);                   \
  }
    DOQ(0, v0) DOQ(1, v1) DOQ(2, v2) DOQ(3, v3)
    DOQ(4, v4) DOQ(5, v5) DOQ(6, v6) DOQ(7, s7)
#undef DOQ

    // ---- gate inputs hoisted above the reduce (LDS broadcast, all lanes)
    float gr, gz, gn;
    if (step < SS) {
      const int tk = tok_lds[step];
      gr = gi_lds[(0 + w) * VV + tk];
      gz = gi_lds[(8 + w) * VV + tk];
      gn = gi_lds[(16 + w) * VV + tk];
    } else {
      const int sel = (step == SS) ? 0 : 24;
      gr = gidec_lds[sel + w];
      gz = gidec_lds[sel + 8 + w];
      gn = gidec_lds[sel + 16 + w];
    }

#pragma unroll
    for (int off = 32; off > 0; off >>= 1) {
      ar += __shfl_xor(ar, off);
      az += __shfl_xor(az, off);
      an += __shfl_xor(an, off);
    }

    if (l == 0) {
      const float xr = gr + ar + br_;
      const float xz = gz + az + bz_;
      const float hn = an + bn_;
      const float rr = 1.f / (1.f + __expf(-xr));
      const float zz = 1.f / (1.f + __expf(-xz));
      const float nn = tanhf(gn + rr * hn);
      const float hnew = (1.f - zz) * nn + zz * hprev;

      _Float16 hf = (_Float16)hnew;
      const unsigned int pk =
          (((unsigned int)(step + 2)) << 16) |
          (unsigned int)__builtin_bit_cast(unsigned short, hf);
      __hip_atomic_store(&hb[(((size_t)((step + 1) & 1)) << 11) + bks + w], pk,
                         __ATOMIC_RELAXED, __HIP_MEMORY_SCOPE_AGENT);
      if (step >= SS) dec_hs[(size_t)(step - SS) * Hh + bks + w] = hnew;
      hprev = hnew;
    }
    // no barrier, no LDS h: waves are fully autonomous
  }
}

// ---------------------------------------------------------------------------
extern "C" void kernel_launch(void* const* d_in, const int* in_sizes, int n_in,
                              void* d_out, int out_size, void* d_ws, size_t ws_size,
                              hipStream_t stream) {
  (void)in_sizes; (void)n_in; (void)out_size; (void)ws_size;
  const int* inputs = (const int*)d_in[0];
  const int* targets = (const int*)d_in[1];
  const float* emb = (const float*)d_in[2];
  const float* enc_w_ih = (const float*)d_in[3];
  const float* enc_w_hh = (const float*)d_in[4];
  const float* enc_b_ih = (const float*)d_in[5];
  const float* enc_b_hh = (const float*)d_in[6];
  const float* dec_w_ih = (const float*)d_in[7];
  const float* dec_w_hh = (const float*)d_in[8];
  const float* dec_b_ih = (const float*)d_in[9];
  const float* dec_b_hh = (const float*)d_in[10];
  const float* fc_w = (const float*)d_in[11];
  const float* fc_b = (const float*)d_in[12];
  float* out = (float*)d_out;

  // workspace layout
  float* giT_enc = (float*)d_ws;                          // [6144][256]
  float* giT_dec = giT_enc + (size_t)6144 * 256;          // [6144][256]
  float* dec_hs = giT_dec + (size_t)6144 * 256;           // [2048][2048]
  unsigned int* hb =
      (unsigned int*)(dec_hs + (size_t)TT * Hh);          // [2][2048] tagged u32

  // per-vocab input-gate tables: giT[r][v] = W_ih[r] . emb[v] + b_ih[r]
  gemm_nt<<<dim3(96, 4), 256, 0, stream>>>(enc_w_ih, emb, enc_b_ih, nullptr,
                                           giT_enc, 3 * Hh, VV, Hh);
  gemm_nt<<<dim3(96, 4), 256, 0, stream>>>(dec_w_ih, emb, dec_b_ih, nullptr,
                                           giT_dec, 3 * Hh, VV, Hh);

  void* args[] = {&giT_enc, &giT_dec, &enc_w_hh, &enc_b_hh, &dec_w_hh,
                  &dec_b_hh, &inputs, &targets, &hb, &dec_hs};
  hipError_t e = hipLaunchCooperativeKernel((void*)recur_kernel, dim3(NB),
                                            dim3(NT), args, 0, stream);
  if (e != hipSuccess) {
    recur_kernel<<<dim3(NB), dim3(NT), 0, stream>>>(
        giT_enc, giT_dec, enc_w_hh, enc_b_hh, dec_w_hh, dec_b_hh, inputs,
        targets, hb, dec_hs);
  }

  // out[t][v] = dec_hs[t] . fc_w[v] + fc_b[v]
  gemm_nt<<<dim3(32, 4), 256, 0, stream>>>(dec_hs, fc_w, nullptr, fc_b, out,
                                           TT, VV, Hh);
}

// Round 7
// 14904.385 us; speedup vs baseline: 3.6886x; 3.6886x over previous
//
#include <hip/hip_runtime.h>
#include <hip/hip_fp16.h>

#define Hh 2048
#define VV 256
#define SS 2048
#define TT 2048
#define NB 128
#define NT 512

typedef _Float16 h4 __attribute__((ext_vector_type(4)));
typedef _Float16 h2 __attribute__((ext_vector_type(2)));
typedef unsigned int u32x4 __attribute__((ext_vector_type(4)));
typedef unsigned short u16x4 __attribute__((ext_vector_type(4)));

#if defined(__has_builtin)
#if __has_builtin(__builtin_amdgcn_fdot2)
#define FDOT2(a, b, c) __builtin_amdgcn_fdot2((a), (b), (c), false)
#endif
#endif
#ifndef FDOT2
#define FDOT2(a, b, c) \
  fmaf((float)(a).x, (float)(b).x, fmaf((float)(a).y, (float)(b).y, (c)))
#endif

#define SH(v, a, b) __builtin_shufflevector((v), (v), (a), (b))

// ---------------------------------------------------------------------------
// Generic NT GEMM: C[M][N] = A[M,K] . B[N,K]^T (+ biasM[m]) (+ biasN[n])
// ---------------------------------------------------------------------------
__global__ __launch_bounds__(256) void gemm_nt(const float* __restrict__ A,
                                               const float* __restrict__ B,
                                               const float* __restrict__ biasM,
                                               const float* __restrict__ biasN,
                                               float* __restrict__ C,
                                               int M, int N, int K) {
  __shared__ __align__(16) float At[32][68];
  __shared__ __align__(16) float Bt[32][68];
  const int t = threadIdx.x;
  const int m0 = blockIdx.x << 6, n0 = blockIdx.y << 6;
  const int r0 = t >> 3, c4 = (t & 7) << 2;
  const int tm = (t >> 4) << 2, tn = (t & 15) << 2;
  float acc[4][4];
#pragma unroll
  for (int i = 0; i < 4; ++i)
#pragma unroll
    for (int j = 0; j < 4; ++j) acc[i][j] = 0.f;

  for (int k0 = 0; k0 < K; k0 += 32) {
    float4 a0 = *(const float4*)&A[(size_t)(m0 + r0) * K + k0 + c4];
    float4 a1 = *(const float4*)&A[(size_t)(m0 + r0 + 32) * K + k0 + c4];
    float4 b0 = *(const float4*)&B[(size_t)(n0 + r0) * K + k0 + c4];
    float4 b1 = *(const float4*)&B[(size_t)(n0 + r0 + 32) * K + k0 + c4];
    __syncthreads();
    At[c4 + 0][r0] = a0.x; At[c4 + 1][r0] = a0.y; At[c4 + 2][r0] = a0.z; At[c4 + 3][r0] = a0.w;
    At[c4 + 0][r0 + 32] = a1.x; At[c4 + 1][r0 + 32] = a1.y; At[c4 + 2][r0 + 32] = a1.z; At[c4 + 3][r0 + 32] = a1.w;
    Bt[c4 + 0][r0] = b0.x; Bt[c4 + 1][r0] = b0.y; Bt[c4 + 2][r0] = b0.z; Bt[c4 + 3][r0] = b0.w;
    Bt[c4 + 0][r0 + 32] = b1.x; Bt[c4 + 1][r0 + 32] = b1.y; Bt[c4 + 2][r0 + 32] = b1.z; Bt[c4 + 3][r0 + 32] = b1.w;
    __syncthreads();
#pragma unroll
    for (int k = 0; k < 32; ++k) {
      float4 av = *(const float4*)&At[k][tm];
      float4 bv = *(const float4*)&Bt[k][tn];
      acc[0][0] = fmaf(av.x, bv.x, acc[0][0]);
      acc[0][1] = fmaf(av.x, bv.y, acc[0][1]);
      acc[0][2] = fmaf(av.x, bv.z, acc[0][2]);
      acc[0][3] = fmaf(av.x, bv.w, acc[0][3]);
      acc[1][0] = fmaf(av.y, bv.x, acc[1][0]);
      acc[1][1] = fmaf(av.y, bv.y, acc[1][1]);
      acc[1][2] = fmaf(av.y, bv.z, acc[1][2]);
      acc[1][3] = fmaf(av.y, bv.w, acc[1][3]);
      acc[2][0] = fmaf(av.z, bv.x, acc[2][0]);
      acc[2][1] = fmaf(av.z, bv.y, acc[2][1]);
      acc[2][2] = fmaf(av.z, bv.z, acc[2][2]);
      acc[2][3] = fmaf(av.z, bv.w, acc[2][3]);
      acc[3][0] = fmaf(av.w, bv.x, acc[3][0]);
      acc[3][1] = fmaf(av.w, bv.y, acc[3][1]);
      acc[3][2] = fmaf(av.w, bv.z, acc[3][2]);
      acc[3][3] = fmaf(av.w, bv.w, acc[3][3]);
    }
  }
#pragma unroll
  for (int i = 0; i < 4; ++i) {
    float bm = biasM ? biasM[m0 + tm + i] : 0.f;
#pragma unroll
    for (int j = 0; j < 4; ++j) {
      float bn = biasN ? biasN[n0 + tn + j] : 0.f;
      C[(size_t)(m0 + tm + i) * N + n0 + tn + j] = acc[i][j] + bm + bn;
    }
  }
}

// ---------------------------------------------------------------------------
// Persistent recurrence kernel — R1 tagged-dataflow protocol, HALF the blocks.
//
// hb: compact uint32[2][2048]; slot = (16-bit epoch tag << 16 | fp16 h bits).
// Reader of step s polls buffer s&1 for tag s+1 (one dwordx4 sc0 sc1 covers
// its 4 slots). Producer at step s publishes tag s+2 into buffer (s+1)&1 via
// relaxed agent store. Init: owner block writes tag 1 to its 16 slots. Tags
// +1-offset; max tag 4097 < 2^16; stale tags from a previous graph replay
// never equal the awaited tag until overwritten by the owner.
//
// NB=128: each block owns 16 h-rows; wave w computes rows bks+2w and
// bks+2w+1 (two register weight sets, 96 VGPRs). This halves the chip-wide
// poll service load (the R2/R6 ledger shows period scales with poll load)
// and halves the per-step straggler population, while leaving the proven R1
// chain (poll -> LDS -> barrier -> dot -> reduce -> publish) untouched.
// After the butterfly reduce every lane holds both rows' totals; lanes 0/1
// run the two gate epilogues in parallel and publish 2 contiguous u32.
//
// Buffer-reuse safety: identical transitive chain to R1 — a producer writes
// epoch e+2 only after polling ALL of e+1, which requires every block to
// have fully read epoch e (each block's tag-(e+1) publish sits after its
// barrier-synchronized staging of epoch e).
// ---------------------------------------------------------------------------
__global__ __launch_bounds__(NT) void recur_kernel(
    const float* __restrict__ giT_enc, const float* __restrict__ giT_dec,
    const float* __restrict__ enc_w_hh, const float* __restrict__ enc_b_hh,
    const float* __restrict__ dec_w_hh, const float* __restrict__ dec_b_hh,
    const int* __restrict__ inputs, const int* __restrict__ targets,
    unsigned int* __restrict__ hb, float* __restrict__ dec_hs) {
  __shared__ __align__(16) float gi_lds[48 * VV];       // 48 KB
  __shared__ __align__(16) _Float16 h16[2][Hh];         // 8 KB (double buffer)
  __shared__ __align__(16) unsigned short tok_lds[SS];  // 4 KB
  __shared__ float gidec_lds[96];

  const int t = threadIdx.x;
  const int b = blockIdx.x;
  const int bks = b << 4;  // 16 rows per block
  const int w = t >> 6, l = t & 63;
  const int ri = (w << 1) + (l & 1);  // this lane's epilogue row (in-block)

  // ---- recurrent weights + biases: two rows per wave, all in registers
  h4 wregA[24], wregB[24];
  float br_, bz_, bn_;
  auto load_wb = [&](const float* W, const float* B) {
#pragma unroll
    for (int g = 0; g < 3; ++g) {
      const float* r0 = W + ((size_t)(g * Hh + bks + (w << 1) + 0)) * Hh + (l << 2);
      const float* r1 = W + ((size_t)(g * Hh + bks + (w << 1) + 1)) * Hh + (l << 2);
#pragma unroll
      for (int q = 0; q < 8; ++q) {
        float4 v0 = *(const float4*)&r0[q * 256];
        float4 v1 = *(const float4*)&r1[q * 256];
        wregA[g * 8 + q] = h4{(_Float16)v0.x, (_Float16)v0.y,
                             (_Float16)v0.z, (_Float16)v0.w};
        wregB[g * 8 + q] = h4{(_Float16)v1.x, (_Float16)v1.y,
                             (_Float16)v1.z, (_Float16)v1.w};
      }
    }
    br_ = B[bks + ri];
    bz_ = B[Hh + bks + ri];
    bn_ = B[2 * Hh + bks + ri];
  };
  load_wb(enc_w_hh, enc_b_hh);

  // ---- stage encoder per-vocab input-gate slice: gi_lds[(g*16+rr)*256 + v]
  for (int r = 0; r < 48; ++r) {
    const int g = r >> 4, rr = r & 15;
    const float4* src = (const float4*)(giT_enc + ((size_t)(g * Hh + bks + rr)) * VV);
    if (t < 64) ((float4*)&gi_lds[r * VV])[t] = src[t];
  }

  // ---- tokens
  for (int u = t; u < SS; u += NT) tok_lds[u] = (unsigned short)inputs[u];

  // ---- decoder input-gates: only tokens {0, targets[1]}
  if (t < 96) {
    const int sel = t / 48, r48 = t % 48;
    const int tk = sel ? targets[1] : 0;
    const int g = r48 >> 4, rr = r48 & 15;
    gidec_lds[sel * 48 + r48] = giT_dec[((size_t)(g * Hh + bks + rr)) * VV + tk];
  }

  // ---- init own h slots: fp16 0.0 (bits 0), tag 1 (buffer 0)
  if (t < 16) {
    __hip_atomic_store(&hb[bks + t], 0x00010000u, __ATOMIC_RELAXED,
                       __HIP_MEMORY_SCOPE_AGENT);
  }
  float hprev = 0.0f;  // lanes 0/1 of wave w: running fp32 h[bks+2w+l]

  for (int step = 0; step < SS + TT; ++step) {
    if (step == SS) load_wb(dec_w_hh, dec_b_hh);  // private regs: no hazard
    const int sb = step & 1;

    // ---- poll the 4 tagged 32-bit slots this thread stages (one dwordx4)
    {
      const unsigned int* addr = hb + ((size_t)sb << 11) + (t << 2);
      const unsigned int want = ((unsigned int)(step + 1)) << 16;
      u32x4 v;
      for (;;) {
        asm volatile(
            "global_load_dwordx4 %0, %1, off sc0 sc1\n\t"
            "s_waitcnt vmcnt(0)"
            : "=&v"(v)
            : "v"(addr)
            : "memory");
        if ((v.x & 0xFFFF0000u) == want && (v.y & 0xFFFF0000u) == want &&
            (v.z & 0xFFFF0000u) == want && (v.w & 0xFFFF0000u) == want)
          break;
        __builtin_amdgcn_s_sleep(1);
      }
      u16x4 hu = {(unsigned short)v.x, (unsigned short)v.y,
                  (unsigned short)v.z, (unsigned short)v.w};
      *(u16x4*)&h16[sb][t << 2] = hu;
    }
    __syncthreads();

    // ---- six gate-row dot products (2 rows x 3 gates), fp16 dot2, fp32 acc
    float arA = 0.f, azA = 0.f, anA = 0.f;
    float arB = 0.f, azB = 0.f, anB = 0.f;
#pragma unroll
    for (int q = 0; q < 8; ++q) {
      const int c = q * 256 + (l << 2);
      h4 hv = *(const h4*)&h16[sb][c];
      h2 hlo = SH(hv, 0, 1);
      h2 hhi = SH(hv, 2, 3);
      h4 a_r = wregA[q], a_z = wregA[8 + q], a_n = wregA[16 + q];
      h4 b_r = wregB[q], b_z = wregB[8 + q], b_n = wregB[16 + q];
      arA = FDOT2(SH(a_r, 0, 1), hlo, arA); arA = FDOT2(SH(a_r, 2, 3), hhi, arA);
      azA = FDOT2(SH(a_z, 0, 1), hlo, azA); azA = FDOT2(SH(a_z, 2, 3), hhi, azA);
      anA = FDOT2(SH(a_n, 0, 1), hlo, anA); anA = FDOT2(SH(a_n, 2, 3), hhi, anA);
      arB = FDOT2(SH(b_r, 0, 1), hlo, arB); arB = FDOT2(SH(b_r, 2, 3), hhi, arB);
      azB = FDOT2(SH(b_z, 0, 1), hlo, azB); azB = FDOT2(SH(b_z, 2, 3), hhi, azB);
      anB = FDOT2(SH(b_n, 0, 1), hlo, anB); anB = FDOT2(SH(b_n, 2, 3), hhi, anB);
    }

    // ---- gate inputs hoisted above the reduce (row-matched via ri)
    float gr, gz, gn;
    if (step < SS) {
      const int tk = tok_lds[step];
      gr = gi_lds[(0 + ri) * VV + tk];
      gz = gi_lds[(16 + ri) * VV + tk];
      gn = gi_lds[(32 + ri) * VV + tk];
    } else {
      const int sel = (step == SS) ? 0 : 48;
      gr = gidec_lds[sel + 0 + ri];
      gz = gidec_lds[sel + 16 + ri];
      gn = gidec_lds[sel + 32 + ri];
    }

#pragma unroll
    for (int off = 32; off > 0; off >>= 1) {
      arA += __shfl_xor(arA, off); azA += __shfl_xor(azA, off); anA += __shfl_xor(anA, off);
      arB += __shfl_xor(arB, off); azB += __shfl_xor(azB, off); anB += __shfl_xor(anB, off);
    }

    if (l < 2) {  // lane 0 -> row bks+2w, lane 1 -> row bks+2w+1
      const float ar = l ? arB : arA;
      const float az = l ? azB : azA;
      const float an = l ? anB : anA;
      const float xr = gr + ar + br_;
      const float xz = gz + az + bz_;
      const float hn = an + bn_;
      const float rr = 1.f / (1.f + __expf(-xr));
      const float zz = 1.f / (1.f + __expf(-xz));
      const float nn = tanhf(gn + rr * hn);
      const float hnew = (1.f - zz) * nn + zz * hprev;

      _Float16 hf = (_Float16)hnew;
      const unsigned int pk =
          (((unsigned int)(step + 2)) << 16) |
          (unsigned int)__builtin_bit_cast(unsigned short, hf);
      __hip_atomic_store(&hb[(((size_t)((step + 1) & 1)) << 11) + bks + ri], pk,
                         __ATOMIC_RELAXED, __HIP_MEMORY_SCOPE_AGENT);
      if (step >= SS) dec_hs[(size_t)(step - SS) * Hh + bks + ri] = hnew;
      hprev = hnew;
    }
    // no trailing barrier: h16 is double-buffered; weights/biases are private
  }
}

// ---------------------------------------------------------------------------
extern "C" void kernel_launch(void* const* d_in, const int* in_sizes, int n_in,
                              void* d_out, int out_size, void* d_ws, size_t ws_size,
                              hipStream_t stream) {
  (void)in_sizes; (void)n_in; (void)out_size; (void)ws_size;
  const int* inputs = (const int*)d_in[0];
  const int* targets = (const int*)d_in[1];
  const float* emb = (const float*)d_in[2];
  const float* enc_w_ih = (const float*)d_in[3];
  const float* enc_w_hh = (const float*)d_in[4];
  const float* enc_b_ih = (const float*)d_in[5];
  const float* enc_b_hh = (const float*)d_in[6];
  const float* dec_w_ih = (const float*)d_in[7];
  const float* dec_w_hh = (const float*)d_in[8];
  const float* dec_b_ih = (const float*)d_in[9];
  const float* dec_b_hh = (const float*)d_in[10];
  const float* fc_w = (const float*)d_in[11];
  const float* fc_b = (const float*)d_in[12];
  float* out = (float*)d_out;

  // workspace layout
  float* giT_enc = (float*)d_ws;                          // [6144][256]
  float* giT_dec = giT_enc + (size_t)6144 * 256;          // [6144][256]
  float* dec_hs = giT_dec + (size_t)6144 * 256;           // [2048][2048]
  unsigned int* hb =
      (unsigned int*)(dec_hs + (size_t)TT * Hh);          // [2][2048] tagged u32

  // per-vocab input-gate tables: giT[r][v] = W_ih[r] . emb[v] + b_ih[r]
  gemm_nt<<<dim3(96, 4), 256, 0, stream>>>(enc_w_ih, emb, enc_b_ih, nullptr,
                                           giT_enc, 3 * Hh, VV, Hh);
  gemm_nt<<<dim3(96, 4), 256, 0, stream>>>(dec_w_ih, emb, dec_b_ih, nullptr,
                                           giT_dec, 3 * Hh, VV, Hh);

  void* args[] = {&giT_enc, &giT_dec, &enc_w_hh, &enc_b_hh, &dec_w_hh,
                  &dec_b_hh, &inputs, &targets, &hb, &dec_hs};
  hipError_t e = hipLaunchCooperativeKernel((void*)recur_kernel, dim3(NB),
                                            dim3(NT), args, 0, stream);
  if (e != hipSuccess) {
    recur_kernel<<<dim3(NB), dim3(NT), 0, stream>>>(
        giT_enc, giT_dec, enc_w_hh, enc_b_hh, dec_w_hh, dec_b_hh, inputs,
        targets, hb, dec_hs);
  }

  // out[t][v] = dec_hs[t] . fc_w[v] + fc_b[v]
  gemm_nt<<<dim3(32, 4), 256, 0, stream>>>(dec_hs, fc_w, nullptr, fc_b, out,
                                           TT, VV, Hh);
}